// Round 4
// baseline (184.746 us; speedup 1.0000x reference)
//
#include <hip/hip_runtime.h>
#include <hip/hip_cooperative_groups.h>
#include <math.h>

namespace cg = cooperative_groups;

// SupConLoss reduced algebraically:
//   sum(sim)      = ||sum_i x_hat_i||^2 / T
//   sum(sim*mask) = sum_c ||S_c||^2 / T,  S_c = sum_{lab==c} x_hat_i
//   n_pos         = sum_c n_c^2
// O(N*H). Labels in [0,10). N=8192, H=768.
//
// R4: profile showed per-iteration time dominated by harness ws-poison
// (~44.5us, untouchable) + our 3-dispatch chain. Fuse everything into ONE
// cooperative kernel (grid=256 blocks = 1/CU, co-resident) with grid.sync()
// between phases; P=256 halves partial traffic vs R3 and keeps it L2-hot.

#define NCLS 10
#define HDIM 768
#define HV4  (HDIM / 4)            // 192 float4 per row
#define CLS_FLOATS (NCLS * HDIM)   // 7680
#define PBLK 256                   // phase-1 blocks == partial count == CUs
#define PSLICES 4
#define NCHUNK (CLS_FLOATS / 256)  // 30

__global__ __launch_bounds__(512) void supcon_fused(
    const float* __restrict__ x, const int* __restrict__ lab,
    float* __restrict__ partials,   // [PBLK][CLS_FLOATS]
    float* __restrict__ csum4,      // [PSLICES][CLS_FLOATS]
    float* __restrict__ out, int N) {
  cg::grid_group grid = cg::this_grid();
  __shared__ float cls[CLS_FLOATS];  // 30720 B
  const int tid = threadIdx.x, lane = tid & 63, wave = tid >> 6;

  // ---------------- phase 1: per-block class sums ----------------
  for (int i = tid; i < CLS_FLOATS; i += blockDim.x) cls[i] = 0.0f;
  __syncthreads();

  const int wavesPerBlock = blockDim.x >> 6;          // 8
  const int gw = blockIdx.x * wavesPerBlock + wave;   // [0, 2048)
  const int totalWaves = PBLK * wavesPerBlock;        // 2048
  const float4* __restrict__ x4 = (const float4*)x;

  for (int pair = gw; 2 * pair < N; pair += totalWaves) {  // 2 iters at N=8192
    const int r0 = 2 * pair, r1 = r0 + 1;
    const size_t b0 = (size_t)r0 * HV4, b1 = (size_t)r1 * HV4;
    float va[12], vb[12];
    {  // issue all 6 dwordx4 loads (both rows) before any dependent use
      float4 t0 = x4[b0 + lane], t1 = x4[b0 + 64 + lane], t2 = x4[b0 + 128 + lane];
      float4 u0 = x4[b1 + lane], u1 = x4[b1 + 64 + lane], u2 = x4[b1 + 128 + lane];
      va[0]=t0.x; va[1]=t0.y; va[2]=t0.z;  va[3]=t0.w;
      va[4]=t1.x; va[5]=t1.y; va[6]=t1.z;  va[7]=t1.w;
      va[8]=t2.x; va[9]=t2.y; va[10]=t2.z; va[11]=t2.w;
      vb[0]=u0.x; vb[1]=u0.y; vb[2]=u0.z;  vb[3]=u0.w;
      vb[4]=u1.x; vb[5]=u1.y; vb[6]=u1.z;  vb[7]=u1.w;
      vb[8]=u2.x; vb[9]=u2.y; vb[10]=u2.z; vb[11]=u2.w;
    }
    const int l0 = lab[r0], l1 = lab[r1];  // wave-uniform
    float ss0 = 0.0f, ss1 = 0.0f;
#pragma unroll
    for (int m = 0; m < 12; ++m) { ss0 += va[m]*va[m]; ss1 += vb[m]*vb[m]; }
#pragma unroll
    for (int off = 32; off >= 1; off >>= 1) {
      ss0 += __shfl_xor(ss0, off, 64);
      ss1 += __shfl_xor(ss1, off, 64);
    }
    const float rn0 = 1.0f / fmaxf(sqrtf(ss0), 1e-12f);  // F.normalize clamp
    const float rn1 = 1.0f / fmaxf(sqrtf(ss1), 1e-12f);
    float* __restrict__ d0 = cls + l0 * HDIM;
    float* __restrict__ d1 = cls + l1 * HDIM;
#pragma unroll
    for (int m = 0; m < 12; ++m) {
      // permuted slot (h-bijection, same for every class): const+lane ->
      // 2 lanes/bank LDS atomics, conflict-free (m136)
      const int s = (m >> 2) * 256 + (m & 3) * 64 + lane;
      atomicAdd(&d0[s], va[m] * rn0);
      atomicAdd(&d1[s], vb[m] * rn1);
    }
  }
  __syncthreads();
  {
    float* __restrict__ outp = partials + (size_t)blockIdx.x * CLS_FLOATS;
    for (int i = tid; i < CLS_FLOATS; i += blockDim.x) outp[i] = cls[i];
  }

  grid.sync();

  // ---------------- phase 2: reduce partials (120 blocks) ----------------
  if (blockIdx.x < NCHUNK * PSLICES) {
    const int chunk = blockIdx.x / PSLICES;     // [0,30)
    const int slice = blockIdx.x % PSLICES;     // [0,4)
    const int slot  = chunk * 256 + (tid & 255);
    const int psub  = tid >> 8;                 // 0/1
    const int p0 = slice * 64 + psub * 32;      // 32 partials per half
    float s[4] = {0.f, 0.f, 0.f, 0.f};
#pragma unroll
    for (int u = 0; u < 32; u += 4) {
      s[0] += partials[(size_t)(p0 + u + 0) * CLS_FLOATS + slot];
      s[1] += partials[(size_t)(p0 + u + 1) * CLS_FLOATS + slot];
      s[2] += partials[(size_t)(p0 + u + 2) * CLS_FLOATS + slot];
      s[3] += partials[(size_t)(p0 + u + 3) * CLS_FLOATS + slot];
    }
    const float sv = (s[0] + s[1]) + (s[2] + s[3]);
    __syncthreads();              // cls reuse: phase-1 reads done
    cls[tid] = sv;                // [psub*256 + slotOff]
    __syncthreads();
    if (psub == 0)
      csum4[(size_t)slice * CLS_FLOATS + slot] = sv + cls[256 + (tid & 255)];
  }

  grid.sync();

  // ---------------- phase 3: finalize (block 0) ----------------
  if (blockIdx.x == 0) {
    __shared__ int scnt[NCLS];
    __shared__ double r0s[8], r1s[8];
    if (tid < NCLS) scnt[tid] = 0;
    __syncthreads();

    // label histogram via per-thread register counters
    int cnt[NCLS];
#pragma unroll
    for (int c = 0; c < NCLS; ++c) cnt[c] = 0;
    for (int i = tid; i < N; i += blockDim.x) {
      const int l = lab[i];
#pragma unroll
      for (int c = 0; c < NCLS; ++c) cnt[c] += (l == c);
    }
#pragma unroll
    for (int c = 0; c < NCLS; ++c) {
      int v = cnt[c];
#pragma unroll
      for (int off = 32; off >= 1; off >>= 1) v += __shfl_xor(v, off, 64);
      if (lane == 0) atomicAdd(&scnt[c], v);
    }

    // sums over slots (slot permutation is an h-bijection applied uniformly
    // per class, so both Sum_c||S_c||^2 and ||Sum_c S_c||^2 are unchanged)
    double masked = 0.0, total = 0.0;
    for (int s = tid; s < HDIM; s += blockDim.x) {
      double tv = 0.0;
#pragma unroll
      for (int c = 0; c < NCLS; ++c) {
        double sv = 0.0;
#pragma unroll
        for (int sl = 0; sl < PSLICES; ++sl)
          sv += (double)csum4[(size_t)sl * CLS_FLOATS + c * HDIM + s];
        masked += sv * sv;
        tv += sv;
      }
      total += tv * tv;
    }
#pragma unroll
    for (int off = 32; off >= 1; off >>= 1) {
      masked += __shfl_xor(masked, off, 64);
      total  += __shfl_xor(total,  off, 64);
    }
    if (lane == 0) { r0s[wave] = masked; r1s[wave] = total; }
    __syncthreads();
    if (tid == 0) {
      double m = 0.0, t = 0.0;
      const int nw = blockDim.x >> 6;
      for (int w = 0; w < nw; ++w) { m += r0s[w]; t += r1s[w]; }
      double n_pos = 0.0;
      for (int c = 0; c < NCLS; ++c) { const double cc = scnt[c]; n_pos += cc * cc; }
      const double T = 0.07;
      const double nn = (double)N * (double)N;
      const double pos_mean = m / (T * n_pos);
      const double neg_mean = (t - m) / (T * (nn - n_pos));
      const double d = neg_mean - pos_mean;
      out[0] = (float)(fmax(d, 0.0) + log1p(exp(-fabs(d))));  // logaddexp(0,d)
    }
  }
}

extern "C" void kernel_launch(void* const* d_in, const int* in_sizes, int n_in,
                              void* d_out, int out_size, void* d_ws, size_t ws_size,
                              hipStream_t stream) {
  const float* x = (const float*)d_in[0];
  const int* lab = (const int*)d_in[1];
  int N = in_sizes[1];  // 8192
  float* partials = (float*)d_ws;                          // 256*7680 floats
  float* csum4 = partials + (size_t)PBLK * CLS_FLOATS;     // 4*7680 floats
  float* outf = (float*)d_out;

  void* args[] = {(void*)&x, (void*)&lab, (void*)&partials,
                  (void*)&csum4, (void*)&outf, (void*)&N};
  hipLaunchCooperativeKernel((void*)supcon_fused, dim3(PBLK), dim3(512),
                             args, 0, stream);
}

// Round 5
// 94.650 us; speedup vs baseline: 1.9519x; 1.9519x over previous
//
#include <hip/hip_runtime.h>
#include <math.h>

// SupConLoss reduced algebraically:
//   sum(sim)      = ||sum_i x_hat_i||^2 / T
//   sum(sim*mask) = sum_c ||S_c||^2 / T,  S_c = sum_{lab==c} x_hat_i
//   n_pos         = sum_c n_c^2
// O(N*H). Labels in [0,10). N=8192, H=768.
//
// R5: cooperative fused kernel regressed (grid.sync ~tens of us + 1 blk/CU).
// Back to 3 dispatches. k1 rebuilt WITHOUT LDS atomics: labels are uniform
// per accumulation step, so readfirstlane + 10-way switch keeps the class
// accumulators in named VGPRs (acc[10], one h-column per thread). Phase A
// computes row norms (wave-per-row, float4); phase B re-reads rows from L2
// and switch-accumulates. LDS use is 32 floats + 32 ints -> no occupancy cap.

#define NCLS 10
#define HDIM 768
#define HV4  (HDIM / 4)            // 192 float4 per row
#define CLS_FLOATS (NCLS * HDIM)   // 7680
#define PBLK 256                   // phase-1 blocks == partial count
#define RPB  32                    // rows per block = N / PBLK
#define PSLICES 4
#define NCHUNK (CLS_FLOATS / 256)  // 30

__global__ __launch_bounds__(768) void k1_fused(
    const float* __restrict__ x, const int* __restrict__ lab,
    float* __restrict__ partials) {
  __shared__ float srn[RPB];
  __shared__ int   slab[RPB];
  const int tid = threadIdx.x, lane = tid & 63, wave = tid >> 6;  // 12 waves
  const int row0 = blockIdx.x * RPB;
  const float4* __restrict__ x4 = (const float4*)x;

  // ---- phase A: row norms, wave-per-row ----
  for (int r = wave; r < RPB; r += 12) {
    const int row = row0 + r;
    const size_t b = (size_t)row * HV4;
    const float4 t0 = x4[b + lane];
    const float4 t1 = x4[b + 64 + lane];
    const float4 t2 = x4[b + 128 + lane];
    float ss = t0.x * t0.x + t0.y * t0.y + t0.z * t0.z + t0.w * t0.w +
               t1.x * t1.x + t1.y * t1.y + t1.z * t1.z + t1.w * t1.w +
               t2.x * t2.x + t2.y * t2.y + t2.z * t2.z + t2.w * t2.w;
#pragma unroll
    for (int off = 32; off >= 1; off >>= 1) ss += __shfl_xor(ss, off, 64);
    if (lane == 0) {
      srn[r] = 1.0f / fmaxf(sqrtf(ss), 1e-12f);  // F.normalize clamp
      slab[r] = lab[row];
    }
  }
  __syncthreads();

  // ---- phase B: one thread per h-column, register class accumulators ----
  float acc[NCLS];
#pragma unroll
  for (int c = 0; c < NCLS; ++c) acc[c] = 0.0f;

#pragma unroll 4
  for (int r = 0; r < RPB; ++r) {
    const float v = x[(size_t)(row0 + r) * HDIM + tid];  // L2-hot re-read
    const float s = srn[r];                              // LDS broadcast
    const int c = __builtin_amdgcn_readfirstlane(slab[r]);  // force uniform
    switch (c) {  // scalar branch; acc[] stays in named VGPRs
      case 0: acc[0] += v * s; break;
      case 1: acc[1] += v * s; break;
      case 2: acc[2] += v * s; break;
      case 3: acc[3] += v * s; break;
      case 4: acc[4] += v * s; break;
      case 5: acc[5] += v * s; break;
      case 6: acc[6] += v * s; break;
      case 7: acc[7] += v * s; break;
      case 8: acc[8] += v * s; break;
      default: acc[9] += v * s; break;
    }
  }

  float* __restrict__ outp = partials + (size_t)blockIdx.x * CLS_FLOATS;
#pragma unroll
  for (int c = 0; c < NCLS; ++c) outp[c * HDIM + tid] = acc[c];  // coalesced
}

// 120 blocks: (chunk, slice) sums its 64-partial slice over a 256-slot chunk.
__global__ __launch_bounds__(256) void k2_reduce(
    const float* __restrict__ partials, float* __restrict__ csum4) {
  const int chunk = blockIdx.x % NCHUNK;
  const int slice = blockIdx.x / NCHUNK;
  const int idx = chunk * 256 + threadIdx.x;
  const int p0 = slice * (PBLK / PSLICES);
  float s[4] = {0.f, 0.f, 0.f, 0.f};
  for (int p = p0; p < p0 + PBLK / PSLICES; p += 4) {
#pragma unroll
    for (int u = 0; u < 4; ++u)
      s[u] += partials[(size_t)(p + u) * CLS_FLOATS + idx];
  }
  csum4[(size_t)slice * CLS_FLOATS + idx] = (s[0] + s[1]) + (s[2] + s[3]);
}

__global__ __launch_bounds__(512) void k3_final(
    const float* __restrict__ csum4, const int* __restrict__ lab,
    float* __restrict__ out, int N) {
  __shared__ int scnt[NCLS];
  __shared__ double r0s[8], r1s[8];
  const int tid = threadIdx.x, lane = tid & 63, wave = tid >> 6;
  if (tid < NCLS) scnt[tid] = 0;
  __syncthreads();

  // label histogram via register counters
  int cnt[NCLS];
#pragma unroll
  for (int c = 0; c < NCLS; ++c) cnt[c] = 0;
  for (int i = tid; i < N; i += blockDim.x) {
    const int l = lab[i];
#pragma unroll
    for (int c = 0; c < NCLS; ++c) cnt[c] += (l == c);
  }
#pragma unroll
  for (int c = 0; c < NCLS; ++c) {
    int v = cnt[c];
#pragma unroll
    for (int off = 32; off >= 1; off >>= 1) v += __shfl_xor(v, off, 64);
    if (lane == 0) atomicAdd(&scnt[c], v);
  }

  double masked = 0.0, total = 0.0;
  for (int h = tid; h < HDIM; h += blockDim.x) {
    double tv = 0.0;
#pragma unroll
    for (int c = 0; c < NCLS; ++c) {
      double sv = 0.0;
#pragma unroll
      for (int sl = 0; sl < PSLICES; ++sl)
        sv += (double)csum4[(size_t)sl * CLS_FLOATS + c * HDIM + h];
      masked += sv * sv;
      tv += sv;
    }
    total += tv * tv;
  }
#pragma unroll
  for (int off = 32; off >= 1; off >>= 1) {
    masked += __shfl_xor(masked, off, 64);
    total  += __shfl_xor(total,  off, 64);
  }
  if (lane == 0) { r0s[wave] = masked; r1s[wave] = total; }
  __syncthreads();
  if (tid == 0) {
    double m = 0.0, t = 0.0;
    const int nw = blockDim.x >> 6;
    for (int w = 0; w < nw; ++w) { m += r0s[w]; t += r1s[w]; }
    double n_pos = 0.0;
    for (int c = 0; c < NCLS; ++c) { const double cc = scnt[c]; n_pos += cc * cc; }
    const double T = 0.07;
    const double nn = (double)N * (double)N;
    const double pos_mean = m / (T * n_pos);
    const double neg_mean = (t - m) / (T * (nn - n_pos));
    const double d = neg_mean - pos_mean;
    out[0] = (float)(fmax(d, 0.0) + log1p(exp(-fabs(d))));  // logaddexp(0,d)
  }
}

extern "C" void kernel_launch(void* const* d_in, const int* in_sizes, int n_in,
                              void* d_out, int out_size, void* d_ws, size_t ws_size,
                              hipStream_t stream) {
  const float* x = (const float*)d_in[0];
  const int* lab = (const int*)d_in[1];
  const int N = in_sizes[1];  // 8192 = PBLK * RPB (fixed problem shape)

  float* partials = (float*)d_ws;                       // 256*7680 floats
  float* csum4 = partials + (size_t)PBLK * CLS_FLOATS;  // 4*7680 floats

  k1_fused<<<PBLK, HDIM, 0, stream>>>(x, lab, partials);
  k2_reduce<<<NCHUNK * PSLICES, 256, 0, stream>>>(partials, csum4);
  k3_final<<<1, 512, 0, stream>>>(csum4, lab, (float*)d_out, N);
}